// Round 13
// baseline (885.196 us; speedup 1.0000x reference)
//
#include <hip/hip_runtime.h>

// UnMaxPoolWithArgmax via counting-sort with atomic slab cursors:
//   passA: per 16384-elem sub-batch, LDS-sort records by 1024 in-batch window
//          buckets ((tg>>14)&1023); each bucket reserves 128B-aligned slabs in
//          its window's contiguous region via atomicAdd(winCursor) and flushes
//          (pads are (0, 0.0f) records -> harmless acc[0]+=0 in passC).
//   passC: one block per 2^14-slot window; count=winCursor[w]*16; PURE
//          STREAMING contiguous read of the window's records, LDS atomicAdd,
//          nontemporal 64 KB store. No directory, no gather, no transpose.
// target tg = (b<<24) | (mask & ~63) | c0 (27 bits); window = tg>>14 (8192).

typedef unsigned int u32;
typedef unsigned short u16;
typedef unsigned long long u64;

typedef int   iv4 __attribute__((ext_vector_type(4)));
typedef float fv4 __attribute__((ext_vector_type(4)));

constexpr long long N_IN = 1LL << 26;      // 67,108,864 elements
constexpr int SBS   = 16384;               // elements per sub-batch
constexpr int NSB   = (int)(N_IN / SBS);   // 4096 sub-batches
constexpr int NBKT  = 1024;                // in-batch window buckets
constexpr int NWIN  = 8192;                // global windows (8 batches * 1024)
constexpr int RSH   = 14;                  // window = 2^14 slots (64 KiB)
constexpr int RSLOTS = 1 << RSH;

constexpr u32 CAP_SLABS = 832;             // slabs per window region (7.8 sigma)
constexpr u32 CAP_REC   = CAP_SLABS * 16;  // 13312 records (104 KiB)

// ---------------- workspace ----------------
constexpr size_t OFF_RECW = 0;                                    // u64[NWIN*CAP_REC] = 832 MiB
constexpr size_t OFF_CUR  = (size_t)NWIN * CAP_REC * 8;           // u32[NWIN] = 32 KiB
constexpr size_t WS_FUSED = OFF_CUR + (size_t)NWIN * 4;

// ============================ passA ============================
__global__ __launch_bounds__(1024) void passA(const float* __restrict__ in,
                                              const int* __restrict__ mask,
                                              u64* __restrict__ recW,
                                              u32* __restrict__ winCursor)
{
    __shared__ u32 cur[NBKT];      // hist -> cursor -> end (4 KiB)
    __shared__ u32 sStart[NBKT];   // bucket start in sRec (4 KiB)
    __shared__ u32 sBase[NBKT];    // bucket's reserved record offset in window region (4 KiB)
    __shared__ u32 wsum[16];
    __shared__ u64 sRec[SBS];      // 128 KiB
    const int tid = threadIdx.x;
    const int sb  = blockIdx.x;    // 0..4095
    const int e0  = sb * SBS + tid * 16;
    const int bb  = e0 >> 23;      // image batch (HWC = 2^23)

    const iv4* m4 = (const iv4*)mask + (e0 >> 2);
    const fv4* v4 = (const fv4*)in + (e0 >> 2);
    iv4 m0 = __builtin_nontemporal_load(m4 + 0);
    iv4 m1 = __builtin_nontemporal_load(m4 + 1);
    iv4 m2 = __builtin_nontemporal_load(m4 + 2);
    iv4 m3 = __builtin_nontemporal_load(m4 + 3);
    fv4 va = __builtin_nontemporal_load(v4 + 0);
    fv4 vb = __builtin_nontemporal_load(v4 + 1);
    fv4 vc = __builtin_nontemporal_load(v4 + 2);
    fv4 vd = __builtin_nontemporal_load(v4 + 3);
    const u32 bbits = ((u32)bb) << 24;
    const u32 c0 = (u32)(e0 & 63);

    u32 tg[16]; float vv[16];
    tg[ 0] = bbits + (((u32)m0.x) & ~63u) + c0 +  0; vv[ 0] = va.x;
    tg[ 1] = bbits + (((u32)m0.y) & ~63u) + c0 +  1; vv[ 1] = va.y;
    tg[ 2] = bbits + (((u32)m0.z) & ~63u) + c0 +  2; vv[ 2] = va.z;
    tg[ 3] = bbits + (((u32)m0.w) & ~63u) + c0 +  3; vv[ 3] = va.w;
    tg[ 4] = bbits + (((u32)m1.x) & ~63u) + c0 +  4; vv[ 4] = vb.x;
    tg[ 5] = bbits + (((u32)m1.y) & ~63u) + c0 +  5; vv[ 5] = vb.y;
    tg[ 6] = bbits + (((u32)m1.z) & ~63u) + c0 +  6; vv[ 6] = vb.z;
    tg[ 7] = bbits + (((u32)m1.w) & ~63u) + c0 +  7; vv[ 7] = vb.w;
    tg[ 8] = bbits + (((u32)m2.x) & ~63u) + c0 +  8; vv[ 8] = vc.x;
    tg[ 9] = bbits + (((u32)m2.y) & ~63u) + c0 +  9; vv[ 9] = vc.y;
    tg[10] = bbits + (((u32)m2.z) & ~63u) + c0 + 10; vv[10] = vc.z;
    tg[11] = bbits + (((u32)m2.w) & ~63u) + c0 + 11; vv[11] = vc.w;
    tg[12] = bbits + (((u32)m3.x) & ~63u) + c0 + 12; vv[12] = vd.x;
    tg[13] = bbits + (((u32)m3.y) & ~63u) + c0 + 13; vv[13] = vd.y;
    tg[14] = bbits + (((u32)m3.z) & ~63u) + c0 + 14; vv[14] = vd.z;
    tg[15] = bbits + (((u32)m3.w) & ~63u) + c0 + 15; vv[15] = vd.w;

    cur[tid] = 0;
    __syncthreads();
#pragma unroll
    for (int j = 0; j < 16; ++j) atomicAdd(&cur[(tg[j] >> RSH) & (NBKT - 1)], 1u);
    __syncthreads();

    // exclusive scan of 1024 counters (one per thread)
    {
        const int lane = tid & 63;
        const int wid  = tid >> 6;          // 0..15
        u32 x = cur[tid];
        u32 s = x;
#pragma unroll
        for (int d = 1; d < 64; d <<= 1) {
            u32 n = __shfl_up(s, (unsigned)d, 64);
            if (lane >= d) s += n;
        }
        if (lane == 63) wsum[wid] = s;
        u32 exw = s - x;
        __syncthreads();
        if (tid == 0) {
            u32 run = 0;
#pragma unroll
            for (int w = 0; w < 16; ++w) { u32 t2 = wsum[w]; wsum[w] = run; run += t2; }
        }
        __syncthreads();
        u32 start = wsum[wid] + exw;
        sStart[tid] = start;
        cur[tid] = start;                   // cursor (ends at bucket end)
    }
    __syncthreads();

#pragma unroll
    for (int j = 0; j < 16; ++j) {
        u32 p = atomicAdd(&cur[(tg[j] >> RSH) & (NBKT - 1)], 1u);
        sRec[p] = ((u64)(tg[j] & (RSLOTS - 1)) << 32) | (u64)__float_as_uint(vv[j]);
    }
    __syncthreads();

    // reserve slab space in this bucket's window region (1 atomic per bucket)
    {
        u32 len   = cur[tid] - sStart[tid];
        u32 slabs = (len + 15u) >> 4;
        u32 sb32  = atomicAdd(&winCursor[(bb << 10) | tid], slabs);
        sBase[tid] = sb32 * 16u;            // record offset in window region
    }
    __syncthreads();

    // flush: 64 groups of 16 lanes; group g flushes buckets g + 64*k.
    // Whole 128B-aligned slabs; pads are (rel=0, val=0.0f) -> harmless.
    const int g  = tid >> 4;
    const int gl = tid & 15;
    for (int k = 0; k < 16; ++k) {
        const int b = g + k * 64;
        const u32 start = sStart[b];
        const u32 len   = cur[b] - start;
        const u32 padded = ((len + 15u) >> 4) << 4;
        const u32 base  = sBase[b];
        if (base + padded > CAP_REC) continue;   // p ~ 1e-26 overflow guard
        u64* dst = recW + (size_t)((bb << 10) | b) * CAP_REC + base;
        for (u32 off = gl; off < padded; off += 16) {
            u64 r = (off < len) ? sRec[start + off] : 0ull;
            dst[off] = r;
        }
    }
}

// ============================ passC (streaming) ============================
__global__ __launch_bounds__(1024, 8) void passC(const u64* __restrict__ recW,
                                                 const u32* __restrict__ winCursor,
                                                 float* __restrict__ out)
{
    __shared__ float acc[RSLOTS];      // 64 KiB
    const int tid = threadIdx.x;
    const int bid = blockIdx.x;
    const int w   = ((bid & 7) << 10) | (bid >> 3);  // XCD-chunked bijective swizzle

    {   // vectorized zero of the accumulator
        fv4 z = {0.f, 0.f, 0.f, 0.f};
        fv4* av = (fv4*)acc;
#pragma unroll
        for (int i = tid; i < RSLOTS / 4; i += 1024) av[i] = z;
    }
    u32 slabs = winCursor[w];
    if (slabs > CAP_SLABS) slabs = CAP_SLABS;
    const u32 count = slabs * 16u;
    const u64* src = recW + (size_t)w * CAP_REC;
    __syncthreads();

    // pure affine stream: coalesced contiguous reads, compiler-pipelined
    for (u32 i = (u32)tid; i < count; i += 1024u) {
        u64 rec = src[i];
        atomicAdd(&acc[(u32)(rec >> 32)], __uint_as_float((u32)rec));
    }
    __syncthreads();

    // nontemporal store: output written once, never re-read this launch
    fv4* o4 = (fv4*)out + ((size_t)w << (RSH - 2));
    const fv4* a4 = (const fv4*)acc;
#pragma unroll
    for (int i = tid; i < RSLOTS / 4; i += 1024)
        __builtin_nontemporal_store(a4[i], o4 + i);
}

// ===================== fallback: direct atomic scatter =====================
__global__ __launch_bounds__(256) void unmaxpool_scatter(
    const float* __restrict__ in, const int* __restrict__ mask,
    float* __restrict__ out)
{
    const long long n4 = N_IN / 4;
    long long gidx = (long long)blockIdx.x * blockDim.x + threadIdx.x;
    const long long stride = (long long)gridDim.x * blockDim.x;
    for (; gidx < n4; gidx += stride) {
        float4 v = reinterpret_cast<const float4*>(in)[gidx];
        int4 m = reinterpret_cast<const int4*>(mask)[gidx];
        long long i0 = gidx * 4;
        u32 ob = ((u32)(i0 >> 23)) << 24;
        u32 c0 = (u32)(i0 & 63);
        atomicAdd(&out[ob + (u32)(m.x & ~63) + c0 + 0], v.x);
        atomicAdd(&out[ob + (u32)(m.y & ~63) + c0 + 1], v.y);
        atomicAdd(&out[ob + (u32)(m.z & ~63) + c0 + 2], v.z);
        atomicAdd(&out[ob + (u32)(m.w & ~63) + c0 + 3], v.w);
    }
}

extern "C" void kernel_launch(void* const* d_in, const int* in_sizes, int n_in,
                              void* d_out, int out_size, void* d_ws, size_t ws_size,
                              hipStream_t stream) {
    const float* in = (const float*)d_in[0];
    const int* mask = (const int*)d_in[1];
    float* out = (float*)d_out;
    char* ws = (char*)d_ws;

    if (d_ws != nullptr && ws_size >= WS_FUSED) {
        u64* recW = (u64*)(ws + OFF_RECW);
        u32* winCursor = (u32*)(ws + OFF_CUR);
        (void)hipMemsetAsync(winCursor, 0, (size_t)NWIN * 4, stream);
        passA<<<NSB, 1024, 0, stream>>>(in, mask, recW, winCursor);
        passC<<<NWIN, 1024, 0, stream>>>(recW, winCursor, out);
    } else {
        (void)hipMemsetAsync(out, 0, (size_t)out_size * sizeof(float), stream);
        unmaxpool_scatter<<<2048, 256, 0, stream>>>(in, mask, out);
    }
}

// Round 14
// 855.482 us; speedup vs baseline: 1.0347x; 1.0347x over previous
//
#include <hip/hip_runtime.h>

// UnMaxPoolWithArgmax, two-pass counting-sort at window granularity:
//   passA: per 8192-elem sub-batch, LDS-sort records by 1024 in-batch window
//          buckets ((tg>>14)&1023); flush contiguous u64 records
//          (rel14<<32 | valbits) + u16 offset directory (write amp ~1).
//   tposeD: transpose directory to window-major (2x16 MB, trivial).
//   passC (v5, DMA-staged gather): one block per 2^14-slot window; 8 batches
//          of 128 chunks, each staged to LDS via global_load_lds width=16
//          (1 wave-instr/wave, register-free -> compiler cannot serialize),
//          double-buffered; predicated ds_add per record; nt 64 KB store.
// target tg = (b<<24) | (mask & ~63) | c0 (27 bits); window = tg>>14 (8192).

typedef unsigned int u32;
typedef unsigned short u16;
typedef unsigned long long u64;

typedef int   iv4 __attribute__((ext_vector_type(4)));
typedef float fv4 __attribute__((ext_vector_type(4)));

constexpr long long N_IN = 1LL << 26;      // 67,108,864 elements
constexpr int SBS   = 8192;                // elements per sub-batch
constexpr int NSB   = (int)(N_IN / SBS);   // 8192 sub-batches
constexpr int NBKT  = 1024;                // in-batch window buckets
constexpr int NWIN  = 8192;                // global windows (8 batches * 1024)
constexpr int RSH   = 14;                  // window = 2^14 slots (64 KiB)
constexpr int RSLOTS = 1 << RSH;
constexpr int SB_PER_B = 1024;             // sub-batches per image batch

// ---------------- workspace ----------------
constexpr size_t OFF_RECA = 0;                                   // u64[2^26] = 512 MiB
constexpr size_t OFF_DIR  = (size_t)N_IN * 8;                    // u16[NSB*NBKT] = 16 MiB
constexpr size_t OFF_DIRT = OFF_DIR + (size_t)NSB * NBKT * 2;    // u16[NWIN*SB_PER_B] = 16 MiB
constexpr size_t WS_FUSED = OFF_DIRT + (size_t)NWIN * SB_PER_B * 2;  // ~544 MiB
// note: passC stages a fixed 16-record slot per chunk; short chunks read into
// the next chunk's records (masked at use) and the final chunk may bleed
// <=16 u64 into the dir region -> still inside ws.

// ============================ passA ============================
__global__ __launch_bounds__(512) void passA(const float* __restrict__ in,
                                             const int* __restrict__ mask,
                                             u64* __restrict__ recA,
                                             u16* __restrict__ dir)
{
    __shared__ u32 cur[NBKT];      // hist -> starts -> cursors (4 KiB)
    __shared__ u32 wsum[8];
    __shared__ u64 sRec[SBS];      // 64 KiB
    const int tid = threadIdx.x;
    const int sb  = blockIdx.x;
    const int e0  = sb * SBS + tid * 16;

    const iv4* m4 = (const iv4*)mask + (e0 >> 2);
    const fv4* v4 = (const fv4*)in + (e0 >> 2);
    iv4 m0 = __builtin_nontemporal_load(m4 + 0);
    iv4 m1 = __builtin_nontemporal_load(m4 + 1);
    iv4 m2 = __builtin_nontemporal_load(m4 + 2);
    iv4 m3 = __builtin_nontemporal_load(m4 + 3);
    fv4 va = __builtin_nontemporal_load(v4 + 0);
    fv4 vb = __builtin_nontemporal_load(v4 + 1);
    fv4 vc = __builtin_nontemporal_load(v4 + 2);
    fv4 vd = __builtin_nontemporal_load(v4 + 3);
    const u32 bbits = ((u32)(e0 >> 23)) << 24;   // batch bits (HWC = 2^23)
    const u32 c0 = (u32)(e0 & 63);

    u32 tg[16]; float vv[16];
    tg[ 0] = bbits + (((u32)m0.x) & ~63u) + c0 +  0; vv[ 0] = va.x;
    tg[ 1] = bbits + (((u32)m0.y) & ~63u) + c0 +  1; vv[ 1] = va.y;
    tg[ 2] = bbits + (((u32)m0.z) & ~63u) + c0 +  2; vv[ 2] = va.z;
    tg[ 3] = bbits + (((u32)m0.w) & ~63u) + c0 +  3; vv[ 3] = va.w;
    tg[ 4] = bbits + (((u32)m1.x) & ~63u) + c0 +  4; vv[ 4] = vb.x;
    tg[ 5] = bbits + (((u32)m1.y) & ~63u) + c0 +  5; vv[ 5] = vb.y;
    tg[ 6] = bbits + (((u32)m1.z) & ~63u) + c0 +  6; vv[ 6] = vb.z;
    tg[ 7] = bbits + (((u32)m1.w) & ~63u) + c0 +  7; vv[ 7] = vb.w;
    tg[ 8] = bbits + (((u32)m2.x) & ~63u) + c0 +  8; vv[ 8] = vc.x;
    tg[ 9] = bbits + (((u32)m2.y) & ~63u) + c0 +  9; vv[ 9] = vc.y;
    tg[10] = bbits + (((u32)m2.z) & ~63u) + c0 + 10; vv[10] = vc.z;
    tg[11] = bbits + (((u32)m2.w) & ~63u) + c0 + 11; vv[11] = vc.w;
    tg[12] = bbits + (((u32)m3.x) & ~63u) + c0 + 12; vv[12] = vd.x;
    tg[13] = bbits + (((u32)m3.y) & ~63u) + c0 + 13; vv[13] = vd.y;
    tg[14] = bbits + (((u32)m3.z) & ~63u) + c0 + 14; vv[14] = vd.z;
    tg[15] = bbits + (((u32)m3.w) & ~63u) + c0 + 15; vv[15] = vd.w;

    cur[2 * tid] = 0;
    cur[2 * tid + 1] = 0;
    __syncthreads();
#pragma unroll
    for (int j = 0; j < 16; ++j) atomicAdd(&cur[(tg[j] >> RSH) & (NBKT - 1)], 1u);
    __syncthreads();

    // exclusive scan of 1024 counters (2 consecutive per thread)
    {
        const int lane = tid & 63;
        const int wid  = tid >> 6;
        u32 a = cur[2 * tid];
        u32 b = cur[2 * tid + 1];
        u32 sum = a + b;
        u32 s = sum;
#pragma unroll
        for (int d = 1; d < 64; d <<= 1) {
            u32 n = __shfl_up(s, (unsigned)d, 64);
            if (lane >= d) s += n;
        }
        if (lane == 63) wsum[wid] = s;
        u32 exw = s - sum;
        __syncthreads();
        if (tid == 0) {
            u32 run = 0;
#pragma unroll
            for (int w = 0; w < 8; ++w) { u32 t2 = wsum[w]; wsum[w] = run; run += t2; }
        }
        __syncthreads();
        u32 start = wsum[wid] + exw;
        dir[(size_t)sb * NBKT + 2 * tid]     = (u16)start;
        dir[(size_t)sb * NBKT + 2 * tid + 1] = (u16)(start + a);
        cur[2 * tid]     = start;          // cursors
        cur[2 * tid + 1] = start + a;
    }
    __syncthreads();

#pragma unroll
    for (int j = 0; j < 16; ++j) {
        u32 p = atomicAdd(&cur[(tg[j] >> RSH) & (NBKT - 1)], 1u);
        sRec[p] = ((u64)(tg[j] & (RSLOTS - 1)) << 32) | (u64)__float_as_uint(vv[j]);
    }
    __syncthreads();
#pragma unroll
    for (int k = 0; k < 16; ++k) {
        int i = tid + k * 512;
        recA[(size_t)sb * SBS + i] = sRec[i];    // contiguous u64 flush
    }
}

// ============================ directory transpose ============================
// dir[bb*1024+sb][1024 lb] -> dirT[bb*1024+lb][1024 sb]; 64x64 u16 tiles.
__global__ __launch_bounds__(256) void tposeD(const u16* __restrict__ dir,
                                              u16* __restrict__ dirT)
{
    __shared__ u16 t[64][65];
    const int tx = threadIdx.x;        // 0..63
    const int ty = threadIdx.y;        // 0..3
    const int bb = blockIdx.z;
    const int sb0 = blockIdx.x * 64;   // 16 tiles
    const int lb0 = blockIdx.y * 64;   // 16 tiles
#pragma unroll
    for (int k = 0; k < 16; ++k) {
        int row = k * 4 + ty;          // sb within tile
        t[row][tx] = dir[((size_t)(bb * SB_PER_B + sb0 + row)) * NBKT + lb0 + tx];
    }
    __syncthreads();
#pragma unroll
    for (int k = 0; k < 16; ++k) {
        int row = k * 4 + ty;          // lb within tile
        dirT[((size_t)(bb * NBKT + lb0 + row)) * SB_PER_B + sb0 + tx] = t[tx][row];
    }
}

// ============================ passC (v5: global_load_lds DMA staging) ============================
__global__ __launch_bounds__(1024) void passC(const u64* __restrict__ recA,
                                              const u16* __restrict__ dirT,
                                              float* __restrict__ out)
{
    __shared__ float acc[RSLOTS];      // 64 KiB
    __shared__ u64 stage[2][2048];     // 2 x 16 KiB staging (16-rec slot/chunk)
    __shared__ u32 cSrc[SB_PER_B];     // 4 KiB
    __shared__ u16 cLen[SB_PER_B];     // 2 KiB
    const int tid = threadIdx.x;
    const int bid = blockIdx.x;
    const int w   = ((bid & 7) << 10) | (bid >> 3);  // XCD-chunked bijective swizzle
    const int bb  = w >> 10;
    const int lb  = w & (NBKT - 1);

    {   // chunk table: two contiguous directory rows
        u32 st = dirT[(size_t)w * SB_PER_B + tid];
        u32 en = (lb == NBKT - 1) ? (u32)SBS : (u32)dirT[(size_t)(w + 1) * SB_PER_B + tid];
        cSrc[tid] = (u32)(bb * SB_PER_B + tid) * (u32)SBS + st;
        cLen[tid] = (u16)(en - st);
    }
    __syncthreads();   // cSrc/cLen visible (needed for batch-0 issue)

    // DMA issue for one 128-chunk batch: wave (tid>>6) stages 8 chunks;
    // 8 lanes per chunk, 16 B per lane -> fixed 16-record slot per chunk.
    // Per-lane GLOBAL address (gather); wave-uniform LDS base (HW scatters
    // lane i at base + i*16). Register-free -> not serializable.
    auto issue = [&](int b, int buf) {
        const int c = (b << 7) + (tid >> 3);          // my chunk
        const u64* gp = recA + (size_t)cSrc[c] + (size_t)((tid & 7) << 1);
        void* lp = (void*)&stage[buf][(size_t)((tid >> 6) << 7)];  // wave-uniform
        __builtin_amdgcn_global_load_lds(
            (const __attribute__((address_space(1))) void*)gp,
            (__attribute__((address_space(3))) void*)lp, 16, 0, 0);
    };

    issue(0, 0);
    {   // vectorized zero of the accumulator (overlaps batch-0 flight)
        fv4 z = {0.f, 0.f, 0.f, 0.f};
        fv4* av = (fv4*)acc;
#pragma unroll
        for (int i = tid; i < RSLOTS / 4; i += 1024) av[i] = z;
    }
    __syncthreads();   // drains vmcnt -> batch 0 staged, acc zeroed

    int buf = 0;
#pragma unroll 1
    for (int b = 0; b < 8; ++b) {
        if (b < 7) issue(b + 1, buf ^ 1);
        // process batch b from stage[buf]: thread t owns records 2t, 2t+1
        {
            const int c   = (b << 7) + (tid >> 3);
            const int len = (int)cLen[c];
            const int r0  = (tid & 7) << 1;
            u64 a0 = stage[buf][2 * tid];
            u64 a1 = stage[buf][2 * tid + 1];
            if (r0 < len)
                atomicAdd(&acc[(u32)(a0 >> 32)], __uint_as_float((u32)a0));
            if (r0 + 1 < len)
                atomicAdd(&acc[(u32)(a1 >> 32)], __uint_as_float((u32)a1));
        }
        __syncthreads();   // batch b+1 staged; stage[buf] free for b+2
        buf ^= 1;
    }

    // rare tails: chunks with len > 16 (P ~ 0.3% at Poisson(8)); thread tid
    // owns chunk tid's tail, serial direct reads (negligible count).
    {
        const int len = (int)cLen[tid];
        for (int off = 16; off < len; ++off) {
            u64 rc = recA[(size_t)cSrc[tid] + off];
            atomicAdd(&acc[(u32)(rc >> 32)], __uint_as_float((u32)rc));
        }
    }
    __syncthreads();

    // nontemporal store: output written once, never re-read this launch
    fv4* o4 = (fv4*)out + ((size_t)w << (RSH - 2));
    const fv4* a4 = (const fv4*)acc;
#pragma unroll
    for (int i = tid; i < RSLOTS / 4; i += 1024)
        __builtin_nontemporal_store(a4[i], o4 + i);
}

// ===================== fallback: direct atomic scatter =====================
__global__ __launch_bounds__(256) void unmaxpool_scatter(
    const float* __restrict__ in, const int* __restrict__ mask,
    float* __restrict__ out)
{
    const long long n4 = N_IN / 4;
    long long gidx = (long long)blockIdx.x * blockDim.x + threadIdx.x;
    const long long stride = (long long)gridDim.x * blockDim.x;
    for (; gidx < n4; gidx += stride) {
        float4 v = reinterpret_cast<const float4*>(in)[gidx];
        int4 m = reinterpret_cast<const int4*>(mask)[gidx];
        long long i0 = gidx * 4;
        u32 ob = ((u32)(i0 >> 23)) << 24;
        u32 c0 = (u32)(i0 & 63);
        atomicAdd(&out[ob + (u32)(m.x & ~63) + c0 + 0], v.x);
        atomicAdd(&out[ob + (u32)(m.y & ~63) + c0 + 1], v.y);
        atomicAdd(&out[ob + (u32)(m.z & ~63) + c0 + 2], v.z);
        atomicAdd(&out[ob + (u32)(m.w & ~63) + c0 + 3], v.w);
    }
}

extern "C" void kernel_launch(void* const* d_in, const int* in_sizes, int n_in,
                              void* d_out, int out_size, void* d_ws, size_t ws_size,
                              hipStream_t stream) {
    const float* in = (const float*)d_in[0];
    const int* mask = (const int*)d_in[1];
    float* out = (float*)d_out;
    char* ws = (char*)d_ws;

    if (d_ws != nullptr && ws_size >= WS_FUSED) {
        u64* recA = (u64*)(ws + OFF_RECA);
        u16* dir  = (u16*)(ws + OFF_DIR);
        u16* dirT = (u16*)(ws + OFF_DIRT);
        passA<<<NSB, 512, 0, stream>>>(in, mask, recA, dir);
        tposeD<<<dim3(16, 16, 8), dim3(64, 4), 0, stream>>>(dir, dirT);
        passC<<<NWIN, 1024, 0, stream>>>(recA, dirT, out);
    } else {
        (void)hipMemsetAsync(out, 0, (size_t)out_size * sizeof(float), stream);
        unmaxpool_scatter<<<2048, 256, 0, stream>>>(in, mask, out);
    }
}

// Round 15
// 744.840 us; speedup vs baseline: 1.1884x; 1.1485x over previous
//
#include <hip/hip_runtime.h>

// UnMaxPoolWithArgmax, two-pass counting-sort at window granularity:
//   passA: per 8192-elem sub-batch, LDS-sort records by 1024 in-batch window
//          buckets ((tg>>14)&1023); flush contiguous u64 records + u16 dir.
//   tposeD: transpose directory to window-major.
//   passC (v6, wave-autonomous DMA pipeline): one block per 2^14-slot window;
//          each wave owns 64 chunks = 8 groups of 8; one global_load_lds
//          width-16 instr stages a 1 KB group into a private 4-slot ring;
//          hand-counted s_waitcnt vmcnt(N) (NO barriers in loop) keeps 4
//          groups in flight per wave = 64 KB/CU; predicated LDS atomicAdd;
//          nontemporal 64 KB store.
// target tg = (b<<24) | (mask & ~63) | c0 (27 bits); window = tg>>14 (8192).

typedef unsigned int u32;
typedef unsigned short u16;
typedef unsigned long long u64;

typedef int   iv4 __attribute__((ext_vector_type(4)));
typedef float fv4 __attribute__((ext_vector_type(4)));

constexpr long long N_IN = 1LL << 26;      // 67,108,864 elements
constexpr int SBS   = 8192;                // elements per sub-batch
constexpr int NSB   = (int)(N_IN / SBS);   // 8192 sub-batches
constexpr int NBKT  = 1024;                // in-batch window buckets
constexpr int NWIN  = 8192;                // global windows (8 batches * 1024)
constexpr int RSH   = 14;                  // window = 2^14 slots (64 KiB)
constexpr int RSLOTS = 1 << RSH;
constexpr int SB_PER_B = 1024;             // sub-batches per image batch

// ---------------- workspace ----------------
constexpr size_t OFF_RECA = 0;                                   // u64[2^26] = 512 MiB
constexpr size_t OFF_DIR  = (size_t)N_IN * 8;                    // u16[NSB*NBKT] = 16 MiB
constexpr size_t OFF_DIRT = OFF_DIR + (size_t)NSB * NBKT * 2;    // u16[NWIN*SB_PER_B] = 16 MiB
constexpr size_t WS_FUSED = OFF_DIRT + (size_t)NWIN * SB_PER_B * 2;  // ~544 MiB
// passC stages fixed 16-record slots; short chunks over-read into following
// records (same window, masked at use); the final chunk may bleed <=16 u64
// into the dir region -> still inside ws.

// ============================ passA ============================
__global__ __launch_bounds__(512) void passA(const float* __restrict__ in,
                                             const int* __restrict__ mask,
                                             u64* __restrict__ recA,
                                             u16* __restrict__ dir)
{
    __shared__ u32 cur[NBKT];      // hist -> starts -> cursors (4 KiB)
    __shared__ u32 wsum[8];
    __shared__ u64 sRec[SBS];      // 64 KiB
    const int tid = threadIdx.x;
    const int sb  = blockIdx.x;
    const int e0  = sb * SBS + tid * 16;

    const iv4* m4 = (const iv4*)mask + (e0 >> 2);
    const fv4* v4 = (const fv4*)in + (e0 >> 2);
    iv4 m0 = __builtin_nontemporal_load(m4 + 0);
    iv4 m1 = __builtin_nontemporal_load(m4 + 1);
    iv4 m2 = __builtin_nontemporal_load(m4 + 2);
    iv4 m3 = __builtin_nontemporal_load(m4 + 3);
    fv4 va = __builtin_nontemporal_load(v4 + 0);
    fv4 vb = __builtin_nontemporal_load(v4 + 1);
    fv4 vc = __builtin_nontemporal_load(v4 + 2);
    fv4 vd = __builtin_nontemporal_load(v4 + 3);
    const u32 bbits = ((u32)(e0 >> 23)) << 24;   // batch bits (HWC = 2^23)
    const u32 c0 = (u32)(e0 & 63);

    u32 tg[16]; float vv[16];
    tg[ 0] = bbits + (((u32)m0.x) & ~63u) + c0 +  0; vv[ 0] = va.x;
    tg[ 1] = bbits + (((u32)m0.y) & ~63u) + c0 +  1; vv[ 1] = va.y;
    tg[ 2] = bbits + (((u32)m0.z) & ~63u) + c0 +  2; vv[ 2] = va.z;
    tg[ 3] = bbits + (((u32)m0.w) & ~63u) + c0 +  3; vv[ 3] = va.w;
    tg[ 4] = bbits + (((u32)m1.x) & ~63u) + c0 +  4; vv[ 4] = vb.x;
    tg[ 5] = bbits + (((u32)m1.y) & ~63u) + c0 +  5; vv[ 5] = vb.y;
    tg[ 6] = bbits + (((u32)m1.z) & ~63u) + c0 +  6; vv[ 6] = vb.z;
    tg[ 7] = bbits + (((u32)m1.w) & ~63u) + c0 +  7; vv[ 7] = vb.w;
    tg[ 8] = bbits + (((u32)m2.x) & ~63u) + c0 +  8; vv[ 8] = vc.x;
    tg[ 9] = bbits + (((u32)m2.y) & ~63u) + c0 +  9; vv[ 9] = vc.y;
    tg[10] = bbits + (((u32)m2.z) & ~63u) + c0 + 10; vv[10] = vc.z;
    tg[11] = bbits + (((u32)m2.w) & ~63u) + c0 + 11; vv[11] = vc.w;
    tg[12] = bbits + (((u32)m3.x) & ~63u) + c0 + 12; vv[12] = vd.x;
    tg[13] = bbits + (((u32)m3.y) & ~63u) + c0 + 13; vv[13] = vd.y;
    tg[14] = bbits + (((u32)m3.z) & ~63u) + c0 + 14; vv[14] = vd.z;
    tg[15] = bbits + (((u32)m3.w) & ~63u) + c0 + 15; vv[15] = vd.w;

    cur[2 * tid] = 0;
    cur[2 * tid + 1] = 0;
    __syncthreads();
#pragma unroll
    for (int j = 0; j < 16; ++j) atomicAdd(&cur[(tg[j] >> RSH) & (NBKT - 1)], 1u);
    __syncthreads();

    // exclusive scan of 1024 counters (2 consecutive per thread)
    {
        const int lane = tid & 63;
        const int wid  = tid >> 6;
        u32 a = cur[2 * tid];
        u32 b = cur[2 * tid + 1];
        u32 sum = a + b;
        u32 s = sum;
#pragma unroll
        for (int d = 1; d < 64; d <<= 1) {
            u32 n = __shfl_up(s, (unsigned)d, 64);
            if (lane >= d) s += n;
        }
        if (lane == 63) wsum[wid] = s;
        u32 exw = s - sum;
        __syncthreads();
        if (tid == 0) {
            u32 run = 0;
#pragma unroll
            for (int w = 0; w < 8; ++w) { u32 t2 = wsum[w]; wsum[w] = run; run += t2; }
        }
        __syncthreads();
        u32 start = wsum[wid] + exw;
        dir[(size_t)sb * NBKT + 2 * tid]     = (u16)start;
        dir[(size_t)sb * NBKT + 2 * tid + 1] = (u16)(start + a);
        cur[2 * tid]     = start;          // cursors
        cur[2 * tid + 1] = start + a;
    }
    __syncthreads();

#pragma unroll
    for (int j = 0; j < 16; ++j) {
        u32 p = atomicAdd(&cur[(tg[j] >> RSH) & (NBKT - 1)], 1u);
        sRec[p] = ((u64)(tg[j] & (RSLOTS - 1)) << 32) | (u64)__float_as_uint(vv[j]);
    }
    __syncthreads();
#pragma unroll
    for (int k = 0; k < 16; ++k) {
        int i = tid + k * 512;
        recA[(size_t)sb * SBS + i] = sRec[i];    // contiguous u64 flush
    }
}

// ============================ directory transpose ============================
__global__ __launch_bounds__(256) void tposeD(const u16* __restrict__ dir,
                                              u16* __restrict__ dirT)
{
    __shared__ u16 t[64][65];
    const int tx = threadIdx.x;        // 0..63
    const int ty = threadIdx.y;        // 0..3
    const int bb = blockIdx.z;
    const int sb0 = blockIdx.x * 64;   // 16 tiles
    const int lb0 = blockIdx.y * 64;   // 16 tiles
#pragma unroll
    for (int k = 0; k < 16; ++k) {
        int row = k * 4 + ty;
        t[row][tx] = dir[((size_t)(bb * SB_PER_B + sb0 + row)) * NBKT + lb0 + tx];
    }
    __syncthreads();
#pragma unroll
    for (int k = 0; k < 16; ++k) {
        int row = k * 4 + ty;
        dirT[((size_t)(bb * NBKT + lb0 + row)) * SB_PER_B + sb0 + tx] = t[tx][row];
    }
}

// ============================ passC (v6: wave-autonomous DMA pipeline) ============================
__global__ __launch_bounds__(1024) void passC(const u64* __restrict__ recA,
                                              const u16* __restrict__ dirT,
                                              float* __restrict__ out)
{
    __shared__ float acc[RSLOTS];        // 64 KiB
    __shared__ u64 stage[16][4][128];    // 16 waves x 4-slot ring x 1 KiB = 64 KiB
    __shared__ u32 cSrc[SB_PER_B];       // 4 KiB
    __shared__ u16 cLen[SB_PER_B];       // 2 KiB
    const int tid  = threadIdx.x;
    const int bid  = blockIdx.x;
    const int w    = ((bid & 7) << 10) | (bid >> 3);  // XCD-chunked bijective swizzle
    const int bb   = w >> 10;
    const int lb   = w & (NBKT - 1);
    const int wv   = tid >> 6;           // wave 0..15
    const int lane = tid & 63;

    {   // chunk table: two contiguous directory rows
        u32 st = dirT[(size_t)w * SB_PER_B + tid];
        u32 en = (lb == NBKT - 1) ? (u32)SBS : (u32)dirT[(size_t)(w + 1) * SB_PER_B + tid];
        cSrc[tid] = (u32)(bb * SB_PER_B + tid) * (u32)SBS + st;
        cLen[tid] = (u16)(en - st);
    }
    {   // vectorized zero of the accumulator
        fv4 z = {0.f, 0.f, 0.f, 0.f};
        fv4* av = (fv4*)acc;
#pragma unroll
        for (int i = tid; i < RSLOTS / 4; i += 1024) av[i] = z;
    }
    __syncthreads();   // tables + acc ready; nothing in flight yet

    // Wave wv owns chunks [wv*64, wv*64+64) in 8 groups of 8.
    // One global_load_lds width-16 instr per group: lane l fetches chunk
    // (group*8 + l>>3), records 2*(l&7), 2*(l&7)+1 (16 B) -> HW scatters to
    // slot base + l*16. u64 slot index j holds chunk j>>4, record j&15.
    const int cw = wv * 64;
    // preload per-lane global addresses for all 8 groups (static unroll)
    const u64* ga[8];
#pragma unroll
    for (int g2 = 0; g2 < 8; ++g2)
        ga[g2] = recA + (size_t)cSrc[cw + g2 * 8 + (lane >> 3)] + (size_t)((lane & 7) << 1);

#define ISSUE(G, SLOT)                                                         \
    __builtin_amdgcn_global_load_lds(                                          \
        (const __attribute__((address_space(1))) void*)ga[G],                  \
        (__attribute__((address_space(3))) void*)&stage[wv][SLOT][0], 16, 0, 0)

#define WAITV(N)                                                               \
    asm volatile("s_waitcnt vmcnt(" #N ")" ::: "memory");                      \
    __builtin_amdgcn_sched_barrier(0)

#define PROC(G)                                                                \
    {                                                                          \
        u64 r0 = stage[wv][(G) & 3][lane];                                     \
        u64 r1 = stage[wv][(G) & 3][lane + 64];                                \
        const int cA = cw + (G) * 8 + (lane >> 4);                             \
        const int cB = cA + 4;                                                 \
        const int ri = lane & 15;                                              \
        if (ri < (int)cLen[cA])                                                \
            atomicAdd(&acc[(u32)(r0 >> 32)], __uint_as_float((u32)r0));        \
        if (ri < (int)cLen[cB])                                                \
            atomicAdd(&acc[(u32)(r1 >> 32)], __uint_as_float((u32)r1));        \
    }

    ISSUE(0, 0); ISSUE(1, 1); ISSUE(2, 2); ISSUE(3, 3);
    WAITV(3); PROC(0); ISSUE(4, 0);
    WAITV(3); PROC(1); ISSUE(5, 1);
    WAITV(3); PROC(2); ISSUE(6, 2);
    WAITV(3); PROC(3); ISSUE(7, 3);
    WAITV(3); PROC(4);
    WAITV(2); PROC(5);
    WAITV(1); PROC(6);
    WAITV(0); PROC(7);

#undef ISSUE
#undef WAITV
#undef PROC

    // rare tails: chunks with len > 16 (P ~ 0.3%); lane l owns chunk cw+l.
    {
        const int c   = cw + lane;
        const int len = (int)cLen[c];
        for (int off = 16; off < len; ++off) {
            u64 rc = recA[(size_t)cSrc[c] + off];
            atomicAdd(&acc[(u32)(rc >> 32)], __uint_as_float((u32)rc));
        }
    }
    __syncthreads();

    // nontemporal store: output written once, never re-read this launch
    fv4* o4 = (fv4*)out + ((size_t)w << (RSH - 2));
    const fv4* a4 = (const fv4*)acc;
#pragma unroll
    for (int i = tid; i < RSLOTS / 4; i += 1024)
        __builtin_nontemporal_store(a4[i], o4 + i);
}

// ===================== fallback: direct atomic scatter =====================
__global__ __launch_bounds__(256) void unmaxpool_scatter(
    const float* __restrict__ in, const int* __restrict__ mask,
    float* __restrict__ out)
{
    const long long n4 = N_IN / 4;
    long long gidx = (long long)blockIdx.x * blockDim.x + threadIdx.x;
    const long long stride = (long long)gridDim.x * blockDim.x;
    for (; gidx < n4; gidx += stride) {
        float4 v = reinterpret_cast<const float4*>(in)[gidx];
        int4 m = reinterpret_cast<const int4*>(mask)[gidx];
        long long i0 = gidx * 4;
        u32 ob = ((u32)(i0 >> 23)) << 24;
        u32 c0 = (u32)(i0 & 63);
        atomicAdd(&out[ob + (u32)(m.x & ~63) + c0 + 0], v.x);
        atomicAdd(&out[ob + (u32)(m.y & ~63) + c0 + 1], v.y);
        atomicAdd(&out[ob + (u32)(m.z & ~63) + c0 + 2], v.z);
        atomicAdd(&out[ob + (u32)(m.w & ~63) + c0 + 3], v.w);
    }
}

extern "C" void kernel_launch(void* const* d_in, const int* in_sizes, int n_in,
                              void* d_out, int out_size, void* d_ws, size_t ws_size,
                              hipStream_t stream) {
    const float* in = (const float*)d_in[0];
    const int* mask = (const int*)d_in[1];
    float* out = (float*)d_out;
    char* ws = (char*)d_ws;

    if (d_ws != nullptr && ws_size >= WS_FUSED) {
        u64* recA = (u64*)(ws + OFF_RECA);
        u16* dir  = (u16*)(ws + OFF_DIR);
        u16* dirT = (u16*)(ws + OFF_DIRT);
        passA<<<NSB, 512, 0, stream>>>(in, mask, recA, dir);
        tposeD<<<dim3(16, 16, 8), dim3(64, 4), 0, stream>>>(dir, dirT);
        passC<<<NWIN, 1024, 0, stream>>>(recA, dirT, out);
    } else {
        (void)hipMemsetAsync(out, 0, (size_t)out_size * sizeof(float), stream);
        unmaxpool_scatter<<<2048, 256, 0, stream>>>(in, mask, out);
    }
}

// Round 16
// 614.609 us; speedup vs baseline: 1.4403x; 1.2119x over previous
//
#include <hip/hip_runtime.h>

// UnMaxPoolWithArgmax, two-pass counting-sort at window granularity:
//   passA: per 8192-elem sub-batch, LDS-sort records by 1024 in-batch window
//          buckets ((tg>>14)&1023); flush contiguous u64 records + u16 dir.
//   tposeD: transpose directory to window-major.
//   passC (v7, asm-pinned 8-deep gather): one block per 2^14-slot window
//          (70 KB LDS -> 2 blocks/CU, 32 waves); per 16-lane group, 8
//          back-to-back inline-asm global_load_dwordx2 (compiler cannot
//          sink/serialize them) -> s_waitcnt vmcnt(0)+sched_barrier ->
//          8 predicated LDS atomicAdd; 2 rounds x 8 chunks; nt 64 KB store.
// target tg = (b<<24) | (mask & ~63) | c0 (27 bits); window = tg>>14 (8192).

typedef unsigned int u32;
typedef unsigned short u16;
typedef unsigned long long u64;

typedef int   iv4 __attribute__((ext_vector_type(4)));
typedef float fv4 __attribute__((ext_vector_type(4)));

constexpr long long N_IN = 1LL << 26;      // 67,108,864 elements
constexpr int SBS   = 8192;                // elements per sub-batch
constexpr int NSB   = (int)(N_IN / SBS);   // 8192 sub-batches
constexpr int NBKT  = 1024;                // in-batch window buckets
constexpr int NWIN  = 8192;                // global windows (8 batches * 1024)
constexpr int RSH   = 14;                  // window = 2^14 slots (64 KiB)
constexpr int RSLOTS = 1 << RSH;
constexpr int SB_PER_B = 1024;             // sub-batches per image batch

// ---------------- workspace ----------------
constexpr size_t OFF_RECA = 0;                                   // u64[2^26] = 512 MiB
constexpr size_t OFF_DIR  = (size_t)N_IN * 8;                    // u16[NSB*NBKT] = 16 MiB
constexpr size_t OFF_DIRT = OFF_DIR + (size_t)NSB * NBKT * 2;    // u16[NWIN*SB_PER_B] = 16 MiB
constexpr size_t WS_FUSED = OFF_DIRT + (size_t)NWIN * SB_PER_B * 2;  // ~544 MiB
// passC's unconditional 16-lane chunk loads may bleed <=15 u64 past a short
// chunk (still in recA) or past recA's end into the dir region -> inside ws.

// ============================ passA ============================
__global__ __launch_bounds__(512) void passA(const float* __restrict__ in,
                                             const int* __restrict__ mask,
                                             u64* __restrict__ recA,
                                             u16* __restrict__ dir)
{
    __shared__ u32 cur[NBKT];      // hist -> starts -> cursors (4 KiB)
    __shared__ u32 wsum[8];
    __shared__ u64 sRec[SBS];      // 64 KiB
    const int tid = threadIdx.x;
    const int sb  = blockIdx.x;
    const int e0  = sb * SBS + tid * 16;

    const iv4* m4 = (const iv4*)mask + (e0 >> 2);
    const fv4* v4 = (const fv4*)in + (e0 >> 2);
    iv4 m0 = __builtin_nontemporal_load(m4 + 0);
    iv4 m1 = __builtin_nontemporal_load(m4 + 1);
    iv4 m2 = __builtin_nontemporal_load(m4 + 2);
    iv4 m3 = __builtin_nontemporal_load(m4 + 3);
    fv4 va = __builtin_nontemporal_load(v4 + 0);
    fv4 vb = __builtin_nontemporal_load(v4 + 1);
    fv4 vc = __builtin_nontemporal_load(v4 + 2);
    fv4 vd = __builtin_nontemporal_load(v4 + 3);
    const u32 bbits = ((u32)(e0 >> 23)) << 24;   // batch bits (HWC = 2^23)
    const u32 c0 = (u32)(e0 & 63);

    u32 tg[16]; float vv[16];
    tg[ 0] = bbits + (((u32)m0.x) & ~63u) + c0 +  0; vv[ 0] = va.x;
    tg[ 1] = bbits + (((u32)m0.y) & ~63u) + c0 +  1; vv[ 1] = va.y;
    tg[ 2] = bbits + (((u32)m0.z) & ~63u) + c0 +  2; vv[ 2] = va.z;
    tg[ 3] = bbits + (((u32)m0.w) & ~63u) + c0 +  3; vv[ 3] = va.w;
    tg[ 4] = bbits + (((u32)m1.x) & ~63u) + c0 +  4; vv[ 4] = vb.x;
    tg[ 5] = bbits + (((u32)m1.y) & ~63u) + c0 +  5; vv[ 5] = vb.y;
    tg[ 6] = bbits + (((u32)m1.z) & ~63u) + c0 +  6; vv[ 6] = vb.z;
    tg[ 7] = bbits + (((u32)m1.w) & ~63u) + c0 +  7; vv[ 7] = vb.w;
    tg[ 8] = bbits + (((u32)m2.x) & ~63u) + c0 +  8; vv[ 8] = vc.x;
    tg[ 9] = bbits + (((u32)m2.y) & ~63u) + c0 +  9; vv[ 9] = vc.y;
    tg[10] = bbits + (((u32)m2.z) & ~63u) + c0 + 10; vv[10] = vc.z;
    tg[11] = bbits + (((u32)m2.w) & ~63u) + c0 + 11; vv[11] = vc.w;
    tg[12] = bbits + (((u32)m3.x) & ~63u) + c0 + 12; vv[12] = vd.x;
    tg[13] = bbits + (((u32)m3.y) & ~63u) + c0 + 13; vv[13] = vd.y;
    tg[14] = bbits + (((u32)m3.z) & ~63u) + c0 + 14; vv[14] = vd.z;
    tg[15] = bbits + (((u32)m3.w) & ~63u) + c0 + 15; vv[15] = vd.w;

    cur[2 * tid] = 0;
    cur[2 * tid + 1] = 0;
    __syncthreads();
#pragma unroll
    for (int j = 0; j < 16; ++j) atomicAdd(&cur[(tg[j] >> RSH) & (NBKT - 1)], 1u);
    __syncthreads();

    // exclusive scan of 1024 counters (2 consecutive per thread)
    {
        const int lane = tid & 63;
        const int wid  = tid >> 6;
        u32 a = cur[2 * tid];
        u32 b = cur[2 * tid + 1];
        u32 sum = a + b;
        u32 s = sum;
#pragma unroll
        for (int d = 1; d < 64; d <<= 1) {
            u32 n = __shfl_up(s, (unsigned)d, 64);
            if (lane >= d) s += n;
        }
        if (lane == 63) wsum[wid] = s;
        u32 exw = s - sum;
        __syncthreads();
        if (tid == 0) {
            u32 run = 0;
#pragma unroll
            for (int w = 0; w < 8; ++w) { u32 t2 = wsum[w]; wsum[w] = run; run += t2; }
        }
        __syncthreads();
        u32 start = wsum[wid] + exw;
        dir[(size_t)sb * NBKT + 2 * tid]     = (u16)start;
        dir[(size_t)sb * NBKT + 2 * tid + 1] = (u16)(start + a);
        cur[2 * tid]     = start;          // cursors
        cur[2 * tid + 1] = start + a;
    }
    __syncthreads();

#pragma unroll
    for (int j = 0; j < 16; ++j) {
        u32 p = atomicAdd(&cur[(tg[j] >> RSH) & (NBKT - 1)], 1u);
        sRec[p] = ((u64)(tg[j] & (RSLOTS - 1)) << 32) | (u64)__float_as_uint(vv[j]);
    }
    __syncthreads();
#pragma unroll
    for (int k = 0; k < 16; ++k) {
        int i = tid + k * 512;
        recA[(size_t)sb * SBS + i] = sRec[i];    // contiguous u64 flush
    }
}

// ============================ directory transpose ============================
__global__ __launch_bounds__(256) void tposeD(const u16* __restrict__ dir,
                                              u16* __restrict__ dirT)
{
    __shared__ u16 t[64][65];
    const int tx = threadIdx.x;        // 0..63
    const int ty = threadIdx.y;        // 0..3
    const int bb = blockIdx.z;
    const int sb0 = blockIdx.x * 64;   // 16 tiles
    const int lb0 = blockIdx.y * 64;   // 16 tiles
#pragma unroll
    for (int k = 0; k < 16; ++k) {
        int row = k * 4 + ty;
        t[row][tx] = dir[((size_t)(bb * SB_PER_B + sb0 + row)) * NBKT + lb0 + tx];
    }
    __syncthreads();
#pragma unroll
    for (int k = 0; k < 16; ++k) {
        int row = k * 4 + ty;
        dirT[((size_t)(bb * NBKT + lb0 + row)) * SB_PER_B + sb0 + tx] = t[tx][row];
    }
}

// ============================ passC (v7: asm-pinned 8-deep gather) ============================
__global__ __launch_bounds__(1024, 8) void passC(const u64* __restrict__ recA,
                                                 const u16* __restrict__ dirT,
                                                 float* __restrict__ out)
{
    __shared__ float acc[RSLOTS];      // 64 KiB
    __shared__ u32 cSrc[SB_PER_B];     // 4 KiB
    __shared__ u16 cLen[SB_PER_B];     // 2 KiB
    const int tid = threadIdx.x;
    const int bid = blockIdx.x;
    const int w   = ((bid & 7) << 10) | (bid >> 3);  // XCD-chunked bijective swizzle
    const int bb  = w >> 10;
    const int lb  = w & (NBKT - 1);

    {   // chunk table: two contiguous directory rows
        u32 st = dirT[(size_t)w * SB_PER_B + tid];
        u32 en = (lb == NBKT - 1) ? (u32)SBS : (u32)dirT[(size_t)(w + 1) * SB_PER_B + tid];
        cSrc[tid] = (u32)(bb * SB_PER_B + tid) * (u32)SBS + st;
        cLen[tid] = (u16)(en - st);
    }
    {   // vectorized zero of the accumulator
        fv4 z = {0.f, 0.f, 0.f, 0.f};
        fv4* av = (fv4*)acc;
#pragma unroll
        for (int i = tid; i < RSLOTS / 4; i += 1024) av[i] = z;
    }
    __syncthreads();

    // 64 groups of 16 lanes; group g owns chunks g + 64*k, k=0..15, processed
    // in 2 rounds of 8. Loads are inline-asm global_load_dwordx2 pinned to
    // "=v" registers -> compiler cannot sink or serialize them: 8 independent
    // loads in flight per THREAD (4 KB/wave, ~128 KB/CU at 32 waves). One
    // s_waitcnt vmcnt(0) + sched_barrier(0) fence, then predicated atomics.
    const int g  = tid >> 4;
    const int gl = tid & 15;
#pragma unroll 1
    for (int r = 0; r < 2; ++r) {
        const int base = g + r * 512;
        u32 sj[8]; int lj[8];
#pragma unroll
        for (int j = 0; j < 8; ++j) {
            const int s = base + j * 64;
            sj[j] = cSrc[s];
            lj[j] = (int)cLen[s];
        }
        u64 v0, v1, v2, v3, v4, v5, v6, v7;
        {
            const u64* a0 = recA + (size_t)sj[0] + gl;
            const u64* a1 = recA + (size_t)sj[1] + gl;
            const u64* a2 = recA + (size_t)sj[2] + gl;
            const u64* a3 = recA + (size_t)sj[3] + gl;
            const u64* a4 = recA + (size_t)sj[4] + gl;
            const u64* a5 = recA + (size_t)sj[5] + gl;
            const u64* a6 = recA + (size_t)sj[6] + gl;
            const u64* a7 = recA + (size_t)sj[7] + gl;
            asm volatile("global_load_dwordx2 %0, %1, off" : "=v"(v0) : "v"(a0));
            asm volatile("global_load_dwordx2 %0, %1, off" : "=v"(v1) : "v"(a1));
            asm volatile("global_load_dwordx2 %0, %1, off" : "=v"(v2) : "v"(a2));
            asm volatile("global_load_dwordx2 %0, %1, off" : "=v"(v3) : "v"(a3));
            asm volatile("global_load_dwordx2 %0, %1, off" : "=v"(v4) : "v"(a4));
            asm volatile("global_load_dwordx2 %0, %1, off" : "=v"(v5) : "v"(a5));
            asm volatile("global_load_dwordx2 %0, %1, off" : "=v"(v6) : "v"(a6));
            asm volatile("global_load_dwordx2 %0, %1, off" : "=v"(v7) : "v"(a7));
            asm volatile("s_waitcnt vmcnt(0)" ::: "memory");
            __builtin_amdgcn_sched_barrier(0);
        }
        if (gl < lj[0]) atomicAdd(&acc[(u32)(v0 >> 32)], __uint_as_float((u32)v0));
        if (gl < lj[1]) atomicAdd(&acc[(u32)(v1 >> 32)], __uint_as_float((u32)v1));
        if (gl < lj[2]) atomicAdd(&acc[(u32)(v2 >> 32)], __uint_as_float((u32)v2));
        if (gl < lj[3]) atomicAdd(&acc[(u32)(v3 >> 32)], __uint_as_float((u32)v3));
        if (gl < lj[4]) atomicAdd(&acc[(u32)(v4 >> 32)], __uint_as_float((u32)v4));
        if (gl < lj[5]) atomicAdd(&acc[(u32)(v5 >> 32)], __uint_as_float((u32)v5));
        if (gl < lj[6]) atomicAdd(&acc[(u32)(v6 >> 32)], __uint_as_float((u32)v6));
        if (gl < lj[7]) atomicAdd(&acc[(u32)(v7 >> 32)], __uint_as_float((u32)v7));
    }

    // rare tails: chunks with len > 16 (P ~ 0.3%); thread tid owns chunk tid.
    {
        const int len = (int)cLen[tid];
        const u32 src = cSrc[tid];
        for (int off = 16; off < len; ++off) {
            u64 rc = recA[(size_t)src + off];
            atomicAdd(&acc[(u32)(rc >> 32)], __uint_as_float((u32)rc));
        }
    }
    __syncthreads();

    // nontemporal store: output written once, never re-read this launch
    fv4* o4 = (fv4*)out + ((size_t)w << (RSH - 2));
    const fv4* a4 = (const fv4*)acc;
#pragma unroll
    for (int i = tid; i < RSLOTS / 4; i += 1024)
        __builtin_nontemporal_store(a4[i], o4 + i);
}

// ===================== fallback: direct atomic scatter =====================
__global__ __launch_bounds__(256) void unmaxpool_scatter(
    const float* __restrict__ in, const int* __restrict__ mask,
    float* __restrict__ out)
{
    const long long n4 = N_IN / 4;
    long long gidx = (long long)blockIdx.x * blockDim.x + threadIdx.x;
    const long long stride = (long long)gridDim.x * blockDim.x;
    for (; gidx < n4; gidx += stride) {
        float4 v = reinterpret_cast<const float4*>(in)[gidx];
        int4 m = reinterpret_cast<const int4*>(mask)[gidx];
        long long i0 = gidx * 4;
        u32 ob = ((u32)(i0 >> 23)) << 24;
        u32 c0 = (u32)(i0 & 63);
        atomicAdd(&out[ob + (u32)(m.x & ~63) + c0 + 0], v.x);
        atomicAdd(&out[ob + (u32)(m.y & ~63) + c0 + 1], v.y);
        atomicAdd(&out[ob + (u32)(m.z & ~63) + c0 + 2], v.z);
        atomicAdd(&out[ob + (u32)(m.w & ~63) + c0 + 3], v.w);
    }
}

extern "C" void kernel_launch(void* const* d_in, const int* in_sizes, int n_in,
                              void* d_out, int out_size, void* d_ws, size_t ws_size,
                              hipStream_t stream) {
    const float* in = (const float*)d_in[0];
    const int* mask = (const int*)d_in[1];
    float* out = (float*)d_out;
    char* ws = (char*)d_ws;

    if (d_ws != nullptr && ws_size >= WS_FUSED) {
        u64* recA = (u64*)(ws + OFF_RECA);
        u16* dir  = (u16*)(ws + OFF_DIR);
        u16* dirT = (u16*)(ws + OFF_DIRT);
        passA<<<NSB, 512, 0, stream>>>(in, mask, recA, dir);
        tposeD<<<dim3(16, 16, 8), dim3(64, 4), 0, stream>>>(dir, dirT);
        passC<<<NWIN, 1024, 0, stream>>>(recA, dirT, out);
    } else {
        (void)hipMemsetAsync(out, 0, (size_t)out_size * sizeof(float), stream);
        unmaxpool_scatter<<<2048, 256, 0, stream>>>(in, mask, out);
    }
}